// Round 4
// baseline (414.812 us; speedup 1.0000x reference)
//
#include <hip/hip_runtime.h>
#include <hip/hip_bf16.h>

// Problem constants (from reference)
#define NB   64          // graphs
#define NPG  2048        // nodes per graph
#define NN   (NB*NPG)    // 131072 total nodes
#define EPG  32768       // edges per graph
#define EE   (NB*EPG)    // 2097152 edges
#define DD   32          // feature dim
#define KK   1024        // kept nodes per graph (ratio 0.5)

typedef unsigned long long u64;
typedef unsigned int u32;

// ---------------------------------------------------------------------------
// K1a: count in-degree per dst node.
// ---------------------------------------------------------------------------
__global__ __launch_bounds__(256) void count_kernel(
    const int* __restrict__ dst, int* __restrict__ counts)
{
    int e = blockIdx.x * 256 + threadIdx.x;
    if (e >= EE) return;
    atomicAdd(&counts[dst[e]], 1);
}

// ---------------------------------------------------------------------------
// K1b: per-graph exclusive scan of counts -> global CSR offsets.
// ---------------------------------------------------------------------------
__global__ __launch_bounds__(256) void scan_kernel(
    const int* __restrict__ counts, int* __restrict__ offsets)
{
    __shared__ int tot[256];
    int b = blockIdx.x;
    int t = threadIdx.x;
    int base = b * NPG + t * 8;
    int loc[8];
    int s = 0;
#pragma unroll
    for (int q = 0; q < 8; q++) { loc[q] = s; s += counts[base + q]; }
    tot[t] = s;
    __syncthreads();
    for (int off = 1; off < 256; off <<= 1) {
        int v = tot[t];
        int u = (t >= off) ? tot[t - off] : 0;
        __syncthreads();
        tot[t] = v + u;
        __syncthreads();
    }
    int excl = (t == 0) ? 0 : tot[t - 1];
#pragma unroll
    for (int q = 0; q < 8; q++) offsets[base + q] = b * EPG + excl + loc[q];
}

// ---------------------------------------------------------------------------
// K1c: scatter src ids into CSR buckets (bucket order arbitrary; fp32 sum
// order diffs vs ref are ~1e-6 relative — far under threshold).
// ---------------------------------------------------------------------------
__global__ __launch_bounds__(256) void fill_kernel(
    const int* __restrict__ src, const int* __restrict__ dst,
    const int* __restrict__ offsets, int* __restrict__ cursor,
    int* __restrict__ edge_ids)
{
    int e = blockIdx.x * 256 + threadIdx.x;
    if (e >= EE) return;
    int t = dst[e];
    int pos = atomicAdd(&cursor[t], 1);
    edge_ids[offsets[t] + pos] = src[e];
}

// ---------------------------------------------------------------------------
// K2: per-node attention score = <x2, y2> / sqrt(32), agg gathered via CSR.
// ---------------------------------------------------------------------------
__global__ __launch_bounds__(256) void score_kernel(
    const float* __restrict__ x,
    const int* __restrict__ counts, const int* __restrict__ offsets,
    const int* __restrict__ edge_ids,
    const float* __restrict__ Wr1, const float* __restrict__ Wl1, const float* __restrict__ b1,
    const float* __restrict__ Wr2, const float* __restrict__ Wl2, const float* __restrict__ b2,
    float* __restrict__ score)
{
    __shared__ float sWr1[DD*DD], sWl1[DD*DD], sWr2[DD*DD], sWl2[DD*DD];
    __shared__ float sb1[DD], sb2[DD];
    for (int i = threadIdx.x; i < DD*DD; i += 256) {
        sWr1[i] = Wr1[i]; sWl1[i] = Wl1[i];
        sWr2[i] = Wr2[i]; sWl2[i] = Wl2[i];
    }
    if (threadIdx.x < DD) { sb1[threadIdx.x] = b1[threadIdx.x]; sb2[threadIdx.x] = b2[threadIdx.x]; }
    __syncthreads();

    int i = blockIdx.x * 256 + threadIdx.x;
    if (i >= NN) return;

    float xv[DD], av[DD];
#pragma unroll
    for (int q = 0; q < DD; q++) av[q] = 0.f;
    {
        const float4* xp = (const float4*)(x + (long long)i * DD);
#pragma unroll
        for (int q = 0; q < 8; q++) {
            float4 v = xp[q]; xv[4*q]=v.x; xv[4*q+1]=v.y; xv[4*q+2]=v.z; xv[4*q+3]=v.w;
        }
    }
    int deg  = counts[i];
    int base = offsets[i];
    for (int k = 0; k < deg; k++) {
        int s = edge_ids[base + k];
        const float4* ap = (const float4*)(x + (long long)s * DD);
#pragma unroll
        for (int q = 0; q < 8; q++) {
            float4 w = ap[q];
            av[4*q]   += w.x; av[4*q+1] += w.y;
            av[4*q+2] += w.z; av[4*q+3] += w.w;
        }
    }

    float sc = 0.f;
    for (int d = 0; d < DD; d++) {
        float a   = sb1[d];
        float b2v = sb2[d];
#pragma unroll
        for (int k = 0; k < DD; k++) {
            a   += xv[k]*sWr1[k*DD+d] + av[k]*sWl1[k*DD+d];
            b2v += xv[k]*sWr2[k*DD+d] + av[k]*sWl2[k*DD+d];
        }
        sc += a * b2v;
    }
    score[i] = sc * 0.17677669529663687f;   // 1/sqrt(32)
}

// ---------------------------------------------------------------------------
// K3: per-graph top-K via bitonic sort of 2048 packed keys in LDS.
// key = (h(score) << 32) | idx, ascending sort; h monotone-decreasing in
// score => descending score, ties -> ascending idx (lax.top_k semantics).
// ---------------------------------------------------------------------------
__global__ __launch_bounds__(1024) void topk_kernel(
    const float* __restrict__ score,
    int* __restrict__ perm_int, int* __restrict__ new_idx,
    float* __restrict__ out_perm,
    float* __restrict__ out_batch,
    float* __restrict__ out_score)
{
    __shared__ u64 keys[NPG];
    int b = blockIdx.x;
    int t = threadIdx.x;
    const float* s = score + (long long)b * NPG;

    for (int j = t; j < NPG; j += 1024) {
        u32 u = __float_as_uint(s[j]);
        u32 h = (u & 0x80000000u) ? u : ~(u | 0x80000000u);
        keys[j] = ((u64)h << 32) | (u32)j;
    }

    for (int k = 2; k <= NPG; k <<= 1) {
        for (int j = k >> 1; j > 0; j >>= 1) {
            __syncthreads();
            int i = ((t & ~(j - 1)) << 1) | (t & (j - 1));
            int l = i | j;
            u64 a = keys[i], c = keys[l];
            bool up = ((i & k) == 0);
            if ((a > c) == up) { keys[i] = c; keys[l] = a; }
        }
    }
    __syncthreads();

    u64 kk = keys[t];
    int idx = (int)(u32)(kk & 0xFFFFFFFFu);
    int g = b * NPG + idx;
    int o = b * KK + t;
    perm_int[o] = g;
    new_idx[g] = o;
    out_perm[o]  = (float)g;
    out_batch[o] = (float)b;
    out_score[o] = s[idx];
}

// ---------------------------------------------------------------------------
// K4: x5 = x[g] + score[g] * (x[g]@Wr3 + agg[g]@Wl3 + b3), kept nodes only.
// ---------------------------------------------------------------------------
__global__ __launch_bounds__(256) void x5_kernel(
    const float* __restrict__ x,
    const int* __restrict__ counts, const int* __restrict__ offsets,
    const int* __restrict__ edge_ids,
    const float* __restrict__ Wr3, const float* __restrict__ Wl3, const float* __restrict__ b3,
    const int* __restrict__ perm_int, const float* __restrict__ score,
    float* __restrict__ out_x5)
{
    __shared__ float sWr[DD*DD], sWl[DD*DD], sb[DD];
    for (int i = threadIdx.x; i < DD*DD; i += 256) { sWr[i] = Wr3[i]; sWl[i] = Wl3[i]; }
    if (threadIdx.x < DD) sb[threadIdx.x] = b3[threadIdx.x];
    __syncthreads();

    int i = blockIdx.x * 256 + threadIdx.x;
    if (i >= NB * KK) return;
    int g = perm_int[i];
    float sc = score[g];

    float xv[DD], av[DD];
#pragma unroll
    for (int q = 0; q < DD; q++) av[q] = 0.f;
    {
        const float4* xp = (const float4*)(x + (long long)g * DD);
#pragma unroll
        for (int q = 0; q < 8; q++) {
            float4 v = xp[q]; xv[4*q]=v.x; xv[4*q+1]=v.y; xv[4*q+2]=v.z; xv[4*q+3]=v.w;
        }
    }
    int deg  = counts[g];
    int base = offsets[g];
    for (int k = 0; k < deg; k++) {
        int s = edge_ids[base + k];
        const float4* ap = (const float4*)(x + (long long)s * DD);
#pragma unroll
        for (int q = 0; q < 8; q++) {
            float4 w = ap[q];
            av[4*q]   += w.x; av[4*q+1] += w.y;
            av[4*q+2] += w.z; av[4*q+3] += w.w;
        }
    }

    float* outp = out_x5 + (long long)i * DD;
    for (int d = 0; d < DD; d++) {
        float a = sb[d];
#pragma unroll
        for (int k = 0; k < DD; k++)
            a += xv[k]*sWr[k*DD+d] + av[k]*sWl[k*DD+d];
        outp[d] = xv[d] + sc * a;
    }
}

// ---------------------------------------------------------------------------
// K5: filter_adj — relabel edges through new_idx, mask dropped ones.
// Overwrites the edge_ids scratch (never reads it).
// ---------------------------------------------------------------------------
__global__ __launch_bounds__(256) void edge_kernel(
    const int* __restrict__ src, const int* __restrict__ dst,
    const float* __restrict__ edge_attr,
    const int* __restrict__ new_idx,
    float* __restrict__ out_ei,    // [2*EE]
    float* __restrict__ out_attr)  // [EE]
{
    int e = blockIdx.x * 256 + threadIdx.x;
    if (e >= EE) return;
    int ns = new_idx[src[e]];
    int nd = new_idx[dst[e]];
    bool valid = (ns >= 0) && (nd >= 0);
    out_ei[e]      = (float)(valid ? ns : -1);
    out_ei[EE + e] = (float)(valid ? nd : -1);
    out_attr[e]    = valid ? edge_attr[e] : 0.f;
}

// ---------------------------------------------------------------------------
extern "C" void kernel_launch(void* const* d_in, const int* in_sizes, int n_in,
                              void* d_out, int out_size, void* d_ws, size_t ws_size,
                              hipStream_t stream)
{
    const float* x     = (const float*)d_in[0];         // fp32 [N, D]
    const int*   src   = (const int*)d_in[1];           // edge_index[0]
    const int*   dst   = ((const int*)d_in[1]) + EE;    // edge_index[1]
    const float* eattr = (const float*)d_in[2];         // fp32 [E]
    // d_in[3] = batch (implied: node g belongs to graph g/NPG)
    const float* Wr1 = (const float*)d_in[4];
    const float* Wl1 = (const float*)d_in[5];
    const float* b1  = (const float*)d_in[6];
    const float* Wr2 = (const float*)d_in[7];
    const float* Wl2 = (const float*)d_in[8];
    const float* b2  = (const float*)d_in[9];
    const float* Wr3 = (const float*)d_in[10];
    const float* Wl3 = (const float*)d_in[11];
    const float* b3  = (const float*)d_in[12];

    // ---- workspace layout (total 2.75 MiB)
    char* ws = (char*)d_ws;
    int*   counts   = (int*)  (ws + 0);                 // NN*4
    int*   offsets  = (int*)  (ws + (size_t)NN*4);
    int*   cursor   = (int*)  (ws + (size_t)NN*8);
    float* score    = (float*)(ws + (size_t)NN*12);
    int*   perm_int = (int*)  (ws + (size_t)NN*16);     // NB*KK*4
    int*   new_idx  = (int*)  (ws + (size_t)NN*16 + (size_t)NB*KK*4);

    // ---- output layout: ONE flat fp32 buffer, reference return order
    float* out = (float*)d_out;
    float* out_x5    = out;                       // NB*KK*DD = 2097152
    float* out_ei    = out + (size_t)NB*KK*DD;    // 2*EE     = 4194304
    float* out_attr  = out_ei + (size_t)2*EE;     // EE       = 2097152
    float* out_batch = out_attr + (size_t)EE;     // NB*KK
    float* out_perm  = out_batch + (size_t)NB*KK; // NB*KK
    float* out_score = out_perm + (size_t)NB*KK;  // NB*KK

    // CSR edge list scratch (EE int32 = 8 MiB) lives in the first half of
    // the out_ei region (2*EE fp32 = 16 MiB); dead before edge_kernel
    // overwrites that region.
    int* edge_ids = (int*)out_ei;

    hipMemsetAsync(counts, 0, (size_t)NN*4, stream);
    hipMemsetAsync(cursor, 0, (size_t)NN*4, stream);
    hipMemsetAsync(new_idx, 0xFF, (size_t)NN*4, stream);   // -1

    count_kernel<<<EE/256, 256, 0, stream>>>(dst, counts);
    scan_kernel <<<NB, 256, 0, stream>>>(counts, offsets);
    fill_kernel <<<EE/256, 256, 0, stream>>>(src, dst, offsets, cursor, edge_ids);

    score_kernel<<<NN/256, 256, 0, stream>>>(x, counts, offsets, edge_ids,
                                             Wr1, Wl1, b1, Wr2, Wl2, b2, score);

    topk_kernel<<<NB, 1024, 0, stream>>>(score, perm_int, new_idx,
                                         out_perm, out_batch, out_score);

    x5_kernel<<<(NB*KK)/256, 256, 0, stream>>>(x, counts, offsets, edge_ids,
                                               Wr3, Wl3, b3, perm_int, score, out_x5);

    edge_kernel<<<EE/256, 256, 0, stream>>>(src, dst, eattr, new_idx, out_ei, out_attr);
}

// Round 5
// 389.461 us; speedup vs baseline: 1.0651x; 1.0651x over previous
//
#include <hip/hip_runtime.h>
#include <hip/hip_bf16.h>

// Problem constants (from reference)
#define NB   64          // graphs
#define NPG  2048        // nodes per graph
#define NN   (NB*NPG)    // 131072 total nodes
#define EPG  32768       // edges per graph
#define EE   (NB*EPG)    // 2097152 edges
#define DD   32          // feature dim
#define KK   1024        // kept nodes per graph (ratio 0.5)

typedef unsigned long long u64;
typedef unsigned int u32;

// ---------------------------------------------------------------------------
// K1a: count in-degree per dst node.
// ---------------------------------------------------------------------------
__global__ __launch_bounds__(256) void count_kernel(
    const int* __restrict__ dst, int* __restrict__ counts)
{
    int e = blockIdx.x * 256 + threadIdx.x;
    if (e >= EE) return;
    atomicAdd(&counts[dst[e]], 1);
}

// ---------------------------------------------------------------------------
// K1b: per-graph exclusive scan of counts -> global CSR offsets.
// ---------------------------------------------------------------------------
__global__ __launch_bounds__(256) void scan_kernel(
    const int* __restrict__ counts, int* __restrict__ offsets)
{
    __shared__ int tot[256];
    int b = blockIdx.x;
    int t = threadIdx.x;
    int base = b * NPG + t * 8;
    int loc[8];
    int s = 0;
#pragma unroll
    for (int q = 0; q < 8; q++) { loc[q] = s; s += counts[base + q]; }
    tot[t] = s;
    __syncthreads();
    for (int off = 1; off < 256; off <<= 1) {
        int v = tot[t];
        int u = (t >= off) ? tot[t - off] : 0;
        __syncthreads();
        tot[t] = v + u;
        __syncthreads();
    }
    int excl = (t == 0) ? 0 : tot[t - 1];
#pragma unroll
    for (int q = 0; q < 8; q++) offsets[base + q] = b * EPG + excl + loc[q];
}

// ---------------------------------------------------------------------------
// K1c: scatter src ids into CSR buckets.
// ---------------------------------------------------------------------------
__global__ __launch_bounds__(256) void fill_kernel(
    const int* __restrict__ src, const int* __restrict__ dst,
    const int* __restrict__ offsets, int* __restrict__ cursor,
    int* __restrict__ edge_ids)
{
    int e = blockIdx.x * 256 + threadIdx.x;
    if (e >= EE) return;
    int t = dst[e];
    int pos = atomicAdd(&cursor[t], 1);
    edge_ids[offsets[t] + pos] = src[e];
}

// ---------------------------------------------------------------------------
// K2a: aggregation — agg[n] = sum_{s in N(n)} x[s]. 8 threads per node,
// thread = (node, 4-float chunk). Per wave step: 8 broadcast index loads +
// 8x128B contiguous row segments; 1M threads hide gather latency.
// ---------------------------------------------------------------------------
__global__ __launch_bounds__(256) void agg_kernel(
    const float* __restrict__ x,
    const int* __restrict__ counts, const int* __restrict__ offsets,
    const int* __restrict__ edge_ids,
    float* __restrict__ agg)
{
    int tid = blockIdx.x * 256 + threadIdx.x;      // NN*8 threads
    int node = tid >> 3;
    int c = (tid & 7) * 4;
    if (node >= NN) return;
    int deg  = counts[node];
    int base = offsets[node];
    float ax = 0.f, ay = 0.f, az = 0.f, aw = 0.f;
    for (int k = 0; k < deg; k++) {
        int s = edge_ids[base + k];
        float4 v = *(const float4*)(x + (long long)s * DD + c);
        ax += v.x; ay += v.y; az += v.z; aw += v.w;
    }
    float4 r; r.x = ax; r.y = ay; r.z = az; r.w = aw;
    *(float4*)(agg + (long long)node * DD + c) = r;
}

// ---------------------------------------------------------------------------
// K2b: per-node attention score = <x2, y2> / sqrt(32). Pure dense streaming.
// ---------------------------------------------------------------------------
__global__ __launch_bounds__(256) void score_kernel(
    const float* __restrict__ x, const float* __restrict__ agg,
    const float* __restrict__ Wr1, const float* __restrict__ Wl1, const float* __restrict__ b1,
    const float* __restrict__ Wr2, const float* __restrict__ Wl2, const float* __restrict__ b2,
    float* __restrict__ score)
{
    __shared__ float sWr1[DD*DD], sWl1[DD*DD], sWr2[DD*DD], sWl2[DD*DD];
    __shared__ float sb1[DD], sb2[DD];
    for (int i = threadIdx.x; i < DD*DD; i += 256) {
        sWr1[i] = Wr1[i]; sWl1[i] = Wl1[i];
        sWr2[i] = Wr2[i]; sWl2[i] = Wl2[i];
    }
    if (threadIdx.x < DD) { sb1[threadIdx.x] = b1[threadIdx.x]; sb2[threadIdx.x] = b2[threadIdx.x]; }
    __syncthreads();

    int i = blockIdx.x * 256 + threadIdx.x;
    if (i >= NN) return;

    float xv[DD], av[DD];
    {
        const float4* xp = (const float4*)(x + (long long)i * DD);
        const float4* ap = (const float4*)(agg + (long long)i * DD);
#pragma unroll
        for (int q = 0; q < 8; q++) {
            float4 v = xp[q]; xv[4*q]=v.x; xv[4*q+1]=v.y; xv[4*q+2]=v.z; xv[4*q+3]=v.w;
            float4 w = ap[q]; av[4*q]=w.x; av[4*q+1]=w.y; av[4*q+2]=w.z; av[4*q+3]=w.w;
        }
    }

    float sc = 0.f;
    for (int d = 0; d < DD; d++) {
        float a   = sb1[d];
        float b2v = sb2[d];
#pragma unroll
        for (int k = 0; k < DD; k++) {
            a   += xv[k]*sWr1[k*DD+d] + av[k]*sWl1[k*DD+d];
            b2v += xv[k]*sWr2[k*DD+d] + av[k]*sWl2[k*DD+d];
        }
        sc += a * b2v;
    }
    score[i] = sc * 0.17677669529663687f;   // 1/sqrt(32)
}

// ---------------------------------------------------------------------------
// K3: per-graph top-K via bitonic sort of 2048 packed keys in LDS.
// key = (h(score) << 32) | idx, ascending sort; h monotone-decreasing in
// score => descending score, ties -> ascending idx (lax.top_k semantics).
// ---------------------------------------------------------------------------
__global__ __launch_bounds__(1024) void topk_kernel(
    const float* __restrict__ score,
    int* __restrict__ perm_int, int* __restrict__ new_idx,
    float* __restrict__ out_perm,
    float* __restrict__ out_batch,
    float* __restrict__ out_score)
{
    __shared__ u64 keys[NPG];
    int b = blockIdx.x;
    int t = threadIdx.x;
    const float* s = score + (long long)b * NPG;

    for (int j = t; j < NPG; j += 1024) {
        u32 u = __float_as_uint(s[j]);
        u32 h = (u & 0x80000000u) ? u : ~(u | 0x80000000u);
        keys[j] = ((u64)h << 32) | (u32)j;
    }

    for (int k = 2; k <= NPG; k <<= 1) {
        for (int j = k >> 1; j > 0; j >>= 1) {
            __syncthreads();
            int i = ((t & ~(j - 1)) << 1) | (t & (j - 1));
            int l = i | j;
            u64 a = keys[i], c = keys[l];
            bool up = ((i & k) == 0);
            if ((a > c) == up) { keys[i] = c; keys[l] = a; }
        }
    }
    __syncthreads();

    u64 kk = keys[t];
    int idx = (int)(u32)(kk & 0xFFFFFFFFu);
    int g = b * NPG + idx;
    int o = b * KK + t;
    perm_int[o] = g;
    new_idx[g] = o;
    out_perm[o]  = (float)g;
    out_batch[o] = (float)b;
    out_score[o] = s[idx];
}

// ---------------------------------------------------------------------------
// K4: x5 = x[g] + score[g] * (x[g]@Wr3 + agg[g]@Wl3 + b3), kept nodes only.
// agg read dense (materialized), only x/agg row gathers via perm.
// ---------------------------------------------------------------------------
__global__ __launch_bounds__(256) void x5_kernel(
    const float* __restrict__ x, const float* __restrict__ agg,
    const float* __restrict__ Wr3, const float* __restrict__ Wl3, const float* __restrict__ b3,
    const int* __restrict__ perm_int, const float* __restrict__ score,
    float* __restrict__ out_x5)
{
    __shared__ float sWr[DD*DD], sWl[DD*DD], sb[DD];
    for (int i = threadIdx.x; i < DD*DD; i += 256) { sWr[i] = Wr3[i]; sWl[i] = Wl3[i]; }
    if (threadIdx.x < DD) sb[threadIdx.x] = b3[threadIdx.x];
    __syncthreads();

    int i = blockIdx.x * 256 + threadIdx.x;
    if (i >= NB * KK) return;
    int g = perm_int[i];
    float sc = score[g];

    float xv[DD], av[DD];
    {
        const float4* xp = (const float4*)(x + (long long)g * DD);
        const float4* ap = (const float4*)(agg + (long long)g * DD);
#pragma unroll
        for (int q = 0; q < 8; q++) {
            float4 v = xp[q]; xv[4*q]=v.x; xv[4*q+1]=v.y; xv[4*q+2]=v.z; xv[4*q+3]=v.w;
            float4 w = ap[q]; av[4*q]=w.x; av[4*q+1]=w.y; av[4*q+2]=w.z; av[4*q+3]=w.w;
        }
    }

    float* outp = out_x5 + (long long)i * DD;
    for (int d = 0; d < DD; d++) {
        float a = sb[d];
#pragma unroll
        for (int k = 0; k < DD; k++)
            a += xv[k]*sWr[k*DD+d] + av[k]*sWl[k*DD+d];
        outp[d] = xv[d] + sc * a;
    }
}

// ---------------------------------------------------------------------------
// K5: filter_adj — relabel edges through new_idx, mask dropped ones.
// Runs last; overwrites the agg (out_ei) and edge_ids (out_attr) scratch.
// ---------------------------------------------------------------------------
__global__ __launch_bounds__(256) void edge_kernel(
    const int* __restrict__ src, const int* __restrict__ dst,
    const float* __restrict__ edge_attr,
    const int* __restrict__ new_idx,
    float* __restrict__ out_ei,    // [2*EE]
    float* __restrict__ out_attr)  // [EE]
{
    int e = blockIdx.x * 256 + threadIdx.x;
    if (e >= EE) return;
    int ns = new_idx[src[e]];
    int nd = new_idx[dst[e]];
    bool valid = (ns >= 0) && (nd >= 0);
    out_ei[e]      = (float)(valid ? ns : -1);
    out_ei[EE + e] = (float)(valid ? nd : -1);
    out_attr[e]    = valid ? edge_attr[e] : 0.f;
}

// ---------------------------------------------------------------------------
extern "C" void kernel_launch(void* const* d_in, const int* in_sizes, int n_in,
                              void* d_out, int out_size, void* d_ws, size_t ws_size,
                              hipStream_t stream)
{
    const float* x     = (const float*)d_in[0];         // fp32 [N, D]
    const int*   src   = (const int*)d_in[1];           // edge_index[0]
    const int*   dst   = ((const int*)d_in[1]) + EE;    // edge_index[1]
    const float* eattr = (const float*)d_in[2];         // fp32 [E]
    // d_in[3] = batch (implied: node g belongs to graph g/NPG)
    const float* Wr1 = (const float*)d_in[4];
    const float* Wl1 = (const float*)d_in[5];
    const float* b1  = (const float*)d_in[6];
    const float* Wr2 = (const float*)d_in[7];
    const float* Wl2 = (const float*)d_in[8];
    const float* b2  = (const float*)d_in[9];
    const float* Wr3 = (const float*)d_in[10];
    const float* Wl3 = (const float*)d_in[11];
    const float* b3  = (const float*)d_in[12];

    // ---- workspace layout (total 2.75 MiB)
    char* ws = (char*)d_ws;
    int*   counts   = (int*)  (ws + 0);                 // NN*4
    int*   offsets  = (int*)  (ws + (size_t)NN*4);
    int*   cursor   = (int*)  (ws + (size_t)NN*8);
    float* score    = (float*)(ws + (size_t)NN*12);
    int*   perm_int = (int*)  (ws + (size_t)NN*16);     // NB*KK*4
    int*   new_idx  = (int*)  (ws + (size_t)NN*16 + (size_t)NB*KK*4);

    // ---- output layout: ONE flat fp32 buffer, reference return order
    float* out = (float*)d_out;
    float* out_x5    = out;                       // NB*KK*DD = 2097152
    float* out_ei    = out + (size_t)NB*KK*DD;    // 2*EE     = 4194304
    float* out_attr  = out_ei + (size_t)2*EE;     // EE       = 2097152
    float* out_batch = out_attr + (size_t)EE;     // NB*KK
    float* out_perm  = out_batch + (size_t)NB*KK; // NB*KK
    float* out_score = out_perm + (size_t)NB*KK;  // NB*KK

    // Scratch aliasing into dead output regions (edge_kernel runs last and
    // overwrites both):
    //   agg      = NN*DD fp32 = 4194304 floats == out_ei region (exact fit)
    //   edge_ids = EE   int32 = 2097152 ints   == out_attr region (exact fit)
    float* agg      = out_ei;
    int*   edge_ids = (int*)out_attr;

    hipMemsetAsync(counts, 0, (size_t)NN*4, stream);
    hipMemsetAsync(cursor, 0, (size_t)NN*4, stream);
    hipMemsetAsync(new_idx, 0xFF, (size_t)NN*4, stream);   // -1

    count_kernel<<<EE/256, 256, 0, stream>>>(dst, counts);
    scan_kernel <<<NB, 256, 0, stream>>>(counts, offsets);
    fill_kernel <<<EE/256, 256, 0, stream>>>(src, dst, offsets, cursor, edge_ids);

    agg_kernel  <<<(NN*8)/256, 256, 0, stream>>>(x, counts, offsets, edge_ids, agg);

    score_kernel<<<NN/256, 256, 0, stream>>>(x, agg, Wr1, Wl1, b1, Wr2, Wl2, b2, score);

    topk_kernel<<<NB, 1024, 0, stream>>>(score, perm_int, new_idx,
                                         out_perm, out_batch, out_score);

    x5_kernel<<<(NB*KK)/256, 256, 0, stream>>>(x, agg, Wr3, Wl3, b3,
                                               perm_int, score, out_x5);

    edge_kernel<<<EE/256, 256, 0, stream>>>(src, dst, eattr, new_idx, out_ei, out_attr);
}

// Round 6
// 273.704 us; speedup vs baseline: 1.5155x; 1.4229x over previous
//
#include <hip/hip_runtime.h>
#include <hip/hip_bf16.h>

// Problem constants (from reference)
#define NB   64          // graphs
#define NPG  2048        // nodes per graph
#define NN   (NB*NPG)    // 131072 total nodes
#define EPG  32768       // edges per graph
#define EE   (NB*EPG)    // 2097152 edges
#define DD   32          // feature dim
#define KK   1024        // kept nodes per graph (ratio 0.5)

typedef unsigned long long u64;
typedef unsigned int u32;

// ---------------------------------------------------------------------------
// K1: fused CSR build — one block per graph. LDS histogram + LDS scan +
// LDS-cursor scatter. All edge_ids writes for a graph come from one CU
// (one XCD) into a contiguous 128 KiB bucket -> no cross-XCD line sharing,
// no write amplification (round-5 fill_kernel showed 105 MB WRITE_SIZE for
// an 8 MiB payload).
// ---------------------------------------------------------------------------
__global__ __launch_bounds__(1024) void build_kernel(
    const int* __restrict__ src, const int* __restrict__ dst,
    int* __restrict__ counts, int* __restrict__ offsets,
    int* __restrict__ edge_ids)
{
    __shared__ int cnt[NPG];      // histogram, then reused as scatter cursor
    __shared__ int tot[1024];     // pair-sum partials for the scan
    int b = blockIdx.x;
    int t = threadIdx.x;

    for (int i = t; i < NPG; i += 1024) cnt[i] = 0;
    __syncthreads();

    const int ebase = b * EPG;
    const int nbase = b * NPG;

    // count + cache edges in registers (each edge read exactly once)
    int dl[32], sl[32];
#pragma unroll
    for (int q = 0; q < 32; q++) {
        int e = ebase + q * 1024 + t;
        dl[q] = dst[e] - nbase;          // local node id [0, 2048)
        sl[q] = src[e];
        atomicAdd(&cnt[dl[q]], 1);
    }
    __syncthreads();

    // exclusive scan of 2048 counters: thread t owns elements 2t, 2t+1
    int c0 = cnt[2*t], c1 = cnt[2*t+1];
    tot[t] = c0 + c1;
    __syncthreads();
    for (int o = 1; o < 1024; o <<= 1) {
        int v = tot[t];
        int u = (t >= o) ? tot[t - o] : 0;
        __syncthreads();
        tot[t] = v + u;
        __syncthreads();
    }
    int excl = (t == 0) ? 0 : tot[t - 1];

    // publish counts/offsets (agg_kernel consumes), seed LDS cursors
    counts[nbase + 2*t]     = c0;
    counts[nbase + 2*t + 1] = c1;
    offsets[nbase + 2*t]     = ebase + excl;
    offsets[nbase + 2*t + 1] = ebase + excl + c0;
    cnt[2*t]     = excl;
    cnt[2*t + 1] = excl + c0;
    __syncthreads();

    // scatter src ids into CSR buckets (bucket order arbitrary; fp32 sum
    // order diffs vs ref are ~1e-6 relative — far under threshold)
#pragma unroll
    for (int q = 0; q < 32; q++) {
        int pos = atomicAdd(&cnt[dl[q]], 1);
        edge_ids[ebase + pos] = sl[q];
    }
}

// ---------------------------------------------------------------------------
// K2a: aggregation — agg[n] = sum_{s in N(n)} x[s]. 8 threads per node,
// thread = (node, 4-float chunk). Per wave step: 8 broadcast index loads +
// 8x128B contiguous row segments; 1M threads hide gather latency.
// ---------------------------------------------------------------------------
__global__ __launch_bounds__(256) void agg_kernel(
    const float* __restrict__ x,
    const int* __restrict__ counts, const int* __restrict__ offsets,
    const int* __restrict__ edge_ids,
    float* __restrict__ agg)
{
    int tid = blockIdx.x * 256 + threadIdx.x;      // NN*8 threads
    int node = tid >> 3;
    int c = (tid & 7) * 4;
    if (node >= NN) return;
    int deg  = counts[node];
    int base = offsets[node];
    float ax = 0.f, ay = 0.f, az = 0.f, aw = 0.f;
    for (int k = 0; k < deg; k++) {
        int s = edge_ids[base + k];
        float4 v = *(const float4*)(x + (long long)s * DD + c);
        ax += v.x; ay += v.y; az += v.z; aw += v.w;
    }
    float4 r; r.x = ax; r.y = ay; r.z = az; r.w = aw;
    *(float4*)(agg + (long long)node * DD + c) = r;
}

// ---------------------------------------------------------------------------
// K2b: per-node attention score = <x2, y2> / sqrt(32). Pure dense streaming.
// ---------------------------------------------------------------------------
__global__ __launch_bounds__(256) void score_kernel(
    const float* __restrict__ x, const float* __restrict__ agg,
    const float* __restrict__ Wr1, const float* __restrict__ Wl1, const float* __restrict__ b1,
    const float* __restrict__ Wr2, const float* __restrict__ Wl2, const float* __restrict__ b2,
    float* __restrict__ score)
{
    __shared__ float sWr1[DD*DD], sWl1[DD*DD], sWr2[DD*DD], sWl2[DD*DD];
    __shared__ float sb1[DD], sb2[DD];
    for (int i = threadIdx.x; i < DD*DD; i += 256) {
        sWr1[i] = Wr1[i]; sWl1[i] = Wl1[i];
        sWr2[i] = Wr2[i]; sWl2[i] = Wl2[i];
    }
    if (threadIdx.x < DD) { sb1[threadIdx.x] = b1[threadIdx.x]; sb2[threadIdx.x] = b2[threadIdx.x]; }
    __syncthreads();

    int i = blockIdx.x * 256 + threadIdx.x;
    if (i >= NN) return;

    float xv[DD], av[DD];
    {
        const float4* xp = (const float4*)(x + (long long)i * DD);
        const float4* ap = (const float4*)(agg + (long long)i * DD);
#pragma unroll
        for (int q = 0; q < 8; q++) {
            float4 v = xp[q]; xv[4*q]=v.x; xv[4*q+1]=v.y; xv[4*q+2]=v.z; xv[4*q+3]=v.w;
            float4 w = ap[q]; av[4*q]=w.x; av[4*q+1]=w.y; av[4*q+2]=w.z; av[4*q+3]=w.w;
        }
    }

    float sc = 0.f;
    for (int d = 0; d < DD; d++) {
        float a   = sb1[d];
        float b2v = sb2[d];
#pragma unroll
        for (int k = 0; k < DD; k++) {
            a   += xv[k]*sWr1[k*DD+d] + av[k]*sWl1[k*DD+d];
            b2v += xv[k]*sWr2[k*DD+d] + av[k]*sWl2[k*DD+d];
        }
        sc += a * b2v;
    }
    score[i] = sc * 0.17677669529663687f;   // 1/sqrt(32)
}

// ---------------------------------------------------------------------------
// K3: per-graph top-K via bitonic sort of 2048 packed keys in LDS.
// key = (h(score) << 32) | idx, ascending sort; h monotone-decreasing in
// score => descending score, ties -> ascending idx (lax.top_k semantics).
// ---------------------------------------------------------------------------
__global__ __launch_bounds__(1024) void topk_kernel(
    const float* __restrict__ score,
    int* __restrict__ perm_int, int* __restrict__ new_idx,
    float* __restrict__ out_perm,
    float* __restrict__ out_batch,
    float* __restrict__ out_score)
{
    __shared__ u64 keys[NPG];
    int b = blockIdx.x;
    int t = threadIdx.x;
    const float* s = score + (long long)b * NPG;

    for (int j = t; j < NPG; j += 1024) {
        u32 u = __float_as_uint(s[j]);
        u32 h = (u & 0x80000000u) ? u : ~(u | 0x80000000u);
        keys[j] = ((u64)h << 32) | (u32)j;
    }

    for (int k = 2; k <= NPG; k <<= 1) {
        for (int j = k >> 1; j > 0; j >>= 1) {
            __syncthreads();
            int i = ((t & ~(j - 1)) << 1) | (t & (j - 1));
            int l = i | j;
            u64 a = keys[i], c = keys[l];
            bool up = ((i & k) == 0);
            if ((a > c) == up) { keys[i] = c; keys[l] = a; }
        }
    }
    __syncthreads();

    u64 kk = keys[t];
    int idx = (int)(u32)(kk & 0xFFFFFFFFu);
    int g = b * NPG + idx;
    int o = b * KK + t;
    perm_int[o] = g;
    new_idx[g] = o;
    out_perm[o]  = (float)g;
    out_batch[o] = (float)b;
    out_score[o] = s[idx];
}

// ---------------------------------------------------------------------------
// K4: x5 = x[g] + score[g] * (x[g]@Wr3 + agg[g]@Wl3 + b3), kept nodes only.
// ---------------------------------------------------------------------------
__global__ __launch_bounds__(256) void x5_kernel(
    const float* __restrict__ x, const float* __restrict__ agg,
    const float* __restrict__ Wr3, const float* __restrict__ Wl3, const float* __restrict__ b3,
    const int* __restrict__ perm_int, const float* __restrict__ score,
    float* __restrict__ out_x5)
{
    __shared__ float sWr[DD*DD], sWl[DD*DD], sb[DD];
    for (int i = threadIdx.x; i < DD*DD; i += 256) { sWr[i] = Wr3[i]; sWl[i] = Wl3[i]; }
    if (threadIdx.x < DD) sb[threadIdx.x] = b3[threadIdx.x];
    __syncthreads();

    int i = blockIdx.x * 256 + threadIdx.x;
    if (i >= NB * KK) return;
    int g = perm_int[i];
    float sc = score[g];

    float xv[DD], av[DD];
    {
        const float4* xp = (const float4*)(x + (long long)g * DD);
        const float4* ap = (const float4*)(agg + (long long)g * DD);
#pragma unroll
        for (int q = 0; q < 8; q++) {
            float4 v = xp[q]; xv[4*q]=v.x; xv[4*q+1]=v.y; xv[4*q+2]=v.z; xv[4*q+3]=v.w;
            float4 w = ap[q]; av[4*q]=w.x; av[4*q+1]=w.y; av[4*q+2]=w.z; av[4*q+3]=w.w;
        }
    }

    float* outp = out_x5 + (long long)i * DD;
    for (int d = 0; d < DD; d++) {
        float a = sb[d];
#pragma unroll
        for (int k = 0; k < DD; k++)
            a += xv[k]*sWr[k*DD+d] + av[k]*sWl[k*DD+d];
        outp[d] = xv[d] + sc * a;
    }
}

// ---------------------------------------------------------------------------
// K5: filter_adj — relabel edges through new_idx, mask dropped ones.
// Runs last; overwrites the agg (out_ei) and edge_ids (out_attr) scratch.
// ---------------------------------------------------------------------------
__global__ __launch_bounds__(256) void edge_kernel(
    const int* __restrict__ src, const int* __restrict__ dst,
    const float* __restrict__ edge_attr,
    const int* __restrict__ new_idx,
    float* __restrict__ out_ei,    // [2*EE]
    float* __restrict__ out_attr)  // [EE]
{
    int e = blockIdx.x * 256 + threadIdx.x;
    if (e >= EE) return;
    int ns = new_idx[src[e]];
    int nd = new_idx[dst[e]];
    bool valid = (ns >= 0) && (nd >= 0);
    out_ei[e]      = (float)(valid ? ns : -1);
    out_ei[EE + e] = (float)(valid ? nd : -1);
    out_attr[e]    = valid ? edge_attr[e] : 0.f;
}

// ---------------------------------------------------------------------------
extern "C" void kernel_launch(void* const* d_in, const int* in_sizes, int n_in,
                              void* d_out, int out_size, void* d_ws, size_t ws_size,
                              hipStream_t stream)
{
    const float* x     = (const float*)d_in[0];         // fp32 [N, D]
    const int*   src   = (const int*)d_in[1];           // edge_index[0]
    const int*   dst   = ((const int*)d_in[1]) + EE;    // edge_index[1]
    const float* eattr = (const float*)d_in[2];         // fp32 [E]
    // d_in[3] = batch (implied: node g belongs to graph g/NPG)
    const float* Wr1 = (const float*)d_in[4];
    const float* Wl1 = (const float*)d_in[5];
    const float* b1  = (const float*)d_in[6];
    const float* Wr2 = (const float*)d_in[7];
    const float* Wl2 = (const float*)d_in[8];
    const float* b2  = (const float*)d_in[9];
    const float* Wr3 = (const float*)d_in[10];
    const float* Wl3 = (const float*)d_in[11];
    const float* b3  = (const float*)d_in[12];

    // ---- workspace layout (total 2.25 MiB)
    char* ws = (char*)d_ws;
    int*   counts   = (int*)  (ws + 0);                 // NN*4
    int*   offsets  = (int*)  (ws + (size_t)NN*4);
    float* score    = (float*)(ws + (size_t)NN*8);
    int*   perm_int = (int*)  (ws + (size_t)NN*12);     // NB*KK*4
    int*   new_idx  = (int*)  (ws + (size_t)NN*12 + (size_t)NB*KK*4);

    // ---- output layout: ONE flat fp32 buffer, reference return order
    float* out = (float*)d_out;
    float* out_x5    = out;                       // NB*KK*DD = 2097152
    float* out_ei    = out + (size_t)NB*KK*DD;    // 2*EE     = 4194304
    float* out_attr  = out_ei + (size_t)2*EE;     // EE       = 2097152
    float* out_batch = out_attr + (size_t)EE;     // NB*KK
    float* out_perm  = out_batch + (size_t)NB*KK; // NB*KK
    float* out_score = out_perm + (size_t)NB*KK;  // NB*KK

    // Scratch aliasing into dead output regions (edge_kernel runs last and
    // overwrites both):
    //   agg      = NN*DD fp32 = 4194304 floats == out_ei region (exact fit)
    //   edge_ids = EE   int32 = 2097152 ints   == out_attr region (exact fit)
    float* agg      = out_ei;
    int*   edge_ids = (int*)out_attr;

    hipMemsetAsync(new_idx, 0xFF, (size_t)NN*4, stream);   // -1

    build_kernel<<<NB, 1024, 0, stream>>>(src, dst, counts, offsets, edge_ids);

    agg_kernel  <<<(NN*8)/256, 256, 0, stream>>>(x, counts, offsets, edge_ids, agg);

    score_kernel<<<NN/256, 256, 0, stream>>>(x, agg, Wr1, Wl1, b1, Wr2, Wl2, b2, score);

    topk_kernel<<<NB, 1024, 0, stream>>>(score, perm_int, new_idx,
                                         out_perm, out_batch, out_score);

    x5_kernel<<<(NB*KK)/256, 256, 0, stream>>>(x, agg, Wr3, Wl3, b3,
                                               perm_int, score, out_x5);

    edge_kernel<<<EE/256, 256, 0, stream>>>(src, dst, eattr, new_idx, out_ei, out_attr);
}